// Round 1
// baseline (15801.595 us; speedup 1.0000x reference)
//
#include <hip/hip_runtime.h>
#include <hip/hip_bf16.h>
#include <stdint.h>

// ---------------------------------------------------------------------------
// Tacotron2 decoder on MI355X.
// Pipeline-persistent design: 256 blocks (1/CU), 4 roles x 64 blocks:
//   role 0 (AX): P0_t   = x_t @ W_ih1^T + b_ih1 + b_hh1          (K=800, padded 1024)
//   role 1 (AF): h1_t   = LSTM1pw(P0_t + h1_{t-1} @ W_hh1^T)     (K=1024)
//   role 2 (B1): P1_t   = h1_t @ W_ih2^T + b_ih2 + b_hh2         (K=1024)
//   role 3 (BF): h2_t   = LSTM2pw(P1_t + h2_{t-1} @ W_hh2^T)     (K=1024)
//   all blocks: out_t   = [h2_t ; du_t] @ Wproj^T + bproj
// One grid barrier per tick; 604 ticks. Weights persistent in VGPRs
// (64 gate cols x 1024 K bf16 = 128 VGPR/lane over 8 waves/block).
// ---------------------------------------------------------------------------

typedef short  bf16x8  __attribute__((ext_vector_type(8)));
typedef float  f32x16  __attribute__((ext_vector_type(16)));

// ---------------- threefry2x32 (exact JAX semantics) ------------------------
__device__ __forceinline__ uint32_t rotl32(uint32_t x, int r) {
  return (x << r) | (x >> (32 - r));
}

__device__ __forceinline__ void tf2x32(uint32_t k0, uint32_t k1,
                                       uint32_t x0, uint32_t x1,
                                       uint32_t& o0, uint32_t& o1) {
  uint32_t k2 = k0 ^ k1 ^ 0x1BD11BDAu;
  x0 += k0; x1 += k1;
#define TF_R(r) { x0 += x1; x1 = rotl32(x1, r); x1 ^= x0; }
  TF_R(13) TF_R(15) TF_R(26) TF_R(6)   x0 += k1; x1 += k2 + 1u;
  TF_R(17) TF_R(29) TF_R(16) TF_R(24)  x0 += k2; x1 += k0 + 2u;
  TF_R(13) TF_R(15) TF_R(26) TF_R(6)   x0 += k0; x1 += k1 + 3u;
  TF_R(17) TF_R(29) TF_R(16) TF_R(24)  x0 += k1; x1 += k2 + 4u;
  TF_R(13) TF_R(15) TF_R(26) TF_R(6)   x0 += k2; x1 += k0 + 5u;
#undef TF_R
  o0 = x0; o1 = x1;
}

// dk1, dk2 = jax.random.split(jax.random.key(42)) ; key data = (0, 42)
__device__ __forceinline__ void dropout_keys(uint32_t& a1, uint32_t& b1,
                                             uint32_t& a2, uint32_t& b2) {
  uint32_t o0, o1, p0, p1;
  tf2x32(0u, 42u, 0u, 2u, o0, o1);   // counts iota(4): x0=[0,1], x1=[2,3]
  tf2x32(0u, 42u, 1u, 3u, p0, p1);
  a1 = o0; b1 = p0;                  // dk1 = bits[0:2] = (out0(0,2), out0(1,3))
  a2 = o1; b2 = p1;                  // dk2 = bits[2:4] = (out1(0,2), out1(1,3))
}

// bernoulli(key,0.5,(601,64,256)): keep(e) <=> top bit of threefry bits == 0
__device__ __forceinline__ bool keep_mask(uint32_t ka, uint32_t kb, uint32_t e) {
  const uint32_t H = 4923392u;       // (601*64*256)/2
  uint32_t o0, o1;
  if (e < H) { tf2x32(ka, kb, e, e + H, o0, o1); return o0 < 0x80000000u; }
  else       { tf2x32(ka, kb, e - H, e, o0, o1); return o1 < 0x80000000u; }
}

__device__ __forceinline__ float sigf(float x)  { return 1.f / (1.f + __expf(-x)); }
__device__ __forceinline__ float tanhf2(float x){ return 2.f / (1.f + __expf(-2.f * x)) - 1.f; }

__device__ __forceinline__ short bf16bits(float f) {
  __hip_bfloat16 h = __float2bfloat16(f);
  short s; __builtin_memcpy(&s, &h, 2);
  return s;
}

// ---------------- prenet layer 1: pn1 = dropout(relu(dec_in @ Wp1^T)) -------
// dec_in[t][b][m]: t==0 -> 0 (go frame), else decoder_inputs[b][m][t-1]
__global__ void prenet1_kernel(const float* __restrict__ dec,
                               const float* __restrict__ Wp1,
                               float* __restrict__ pn1) {
  const int t = blockIdx.x;          // 0..599
  const int tid = threadIdx.x;
  __shared__ float          sdec[64][81];
  __shared__ __hip_bfloat16 sw1[256][80];
  for (int idx = tid; idx < 64 * 80; idx += 256) {
    int b = idx / 80, m = idx - b * 80;
    sdec[b][m] = (t == 0) ? 0.f : dec[b * 48000 + m * 600 + (t - 1)];
  }
  for (int idx = tid; idx < 256 * 80; idx += 256) {
    int j = idx / 80, k = idx - j * 80;
    sw1[j][k] = __float2bfloat16(Wp1[idx]);
  }
  __syncthreads();
  uint32_t ka, kb, ka2, kb2;
  dropout_keys(ka, kb, ka2, kb2);
  const int b  = tid & 63;
  const int jg = tid >> 6;
  for (int jj = 0; jj < 64; ++jj) {
    const int j = jg * 64 + jj;
    float acc = 0.f;
    #pragma unroll
    for (int k = 0; k < 80; ++k)
      acc += sdec[b][k] * __bfloat162float(sw1[j][k]);
    const uint32_t e = (uint32_t)((t * 64 + b) * 256 + j);
    pn1[(t * 64 + b) * 256 + j] =
        keep_mask(ka, kb, e) ? 2.f * fmaxf(acc, 0.f) : 0.f;
  }
}

// ---------------- prenet layer 2 -> X[t][b][0..255] (bf16) ------------------
__global__ void prenet2_kernel(const float* __restrict__ pn1,
                               const float* __restrict__ Wp2,
                               __hip_bfloat16* __restrict__ X) {
  const int t  = blockIdx.x;         // 0..599
  const int j0 = blockIdx.y * 32;    // column octant
  const int tid = threadIdx.x;
  __shared__ __hip_bfloat16 sact[64][258];
  __shared__ __hip_bfloat16 sw[32][256];
  for (int idx = tid; idx < 64 * 256; idx += 256) {
    int b = idx >> 8, k = idx & 255;
    sact[b][k] = __float2bfloat16(pn1[(t * 64 + b) * 256 + k]);
  }
  for (int idx = tid; idx < 32 * 256; idx += 256) {
    int r = idx >> 8, k = idx & 255;
    sw[r][k] = __float2bfloat16(Wp2[(j0 + r) * 256 + k]);
  }
  __syncthreads();
  uint32_t ka, kb, ka2, kb2;
  dropout_keys(ka, kb, ka2, kb2);
  const int b  = tid & 63;
  const int jg = tid >> 6;
  float acc[8];
  #pragma unroll
  for (int c = 0; c < 8; ++c) acc[c] = 0.f;
  for (int k = 0; k < 256; ++k) {
    const float a = __bfloat162float(sact[b][k]);
    #pragma unroll
    for (int c = 0; c < 8; ++c)
      acc[c] += a * __bfloat162float(sw[jg * 8 + c][k]);
  }
  #pragma unroll
  for (int c = 0; c < 8; ++c) {
    const int j = j0 + jg * 8 + c;
    const uint32_t e = (uint32_t)((t * 64 + b) * 256 + j);
    const float v = keep_mask(ka2, kb2, e) ? 2.f * fmaxf(acc[c], 0.f) : 0.f;
    X[(t * 64 + b) * 1024 + j] = __float2bfloat16(v);
  }
}

// ---------------- X[t][b][256..799] = dur[b][t][:], [800..1023] = 0 ---------
__global__ void xfill_kernel(const float* __restrict__ dur,
                             __hip_bfloat16* __restrict__ X) {
  const int idx = blockIdx.x * 256 + threadIdx.x;   // < 600*64*768 exactly
  const int t  = idx / 49152;
  const int r  = idx - t * 49152;
  const int b  = r / 768;
  const int kk = r - b * 768;
  const float v = (kk < 544) ? dur[(b * 600 + t) * 544 + kk] : 0.f;
  X[(t * 64 + b) * 1024 + 256 + kk] = __float2bfloat16(v);
}

__global__ void wprojcvt_kernel(const float* __restrict__ W,
                                __hip_bfloat16* __restrict__ Wb) {
  const int idx = blockIdx.x * 256 + threadIdx.x;   // < 80*1568 exactly
  Wb[idx] = __float2bfloat16(W[idx]);
}

// ---------------- persistent pipelined recurrence ---------------------------
__launch_bounds__(512, 2)
__global__ void persist_kernel(
    const float* __restrict__ Wih1, const float* __restrict__ Whh1,
    const float* __restrict__ bih1, const float* __restrict__ bhh1,
    const float* __restrict__ Wih2, const float* __restrict__ Whh2,
    const float* __restrict__ bih2, const float* __restrict__ bhh2,
    const __hip_bfloat16* __restrict__ WprojB, const float* __restrict__ bproj,
    const __hip_bfloat16* __restrict__ Xbuf,
    float* __restrict__ P0, float* __restrict__ P1,
    __hip_bfloat16* __restrict__ h1buf, __hip_bfloat16* __restrict__ h2buf,
    float* __restrict__ out, unsigned int* __restrict__ bar) {
  const int bid  = blockIdx.x;
  const int role = bid >> 6;          // 0:AX 1:AF 2:B1 3:BF
  const int sub  = bid & 63;
  const int tid  = threadIdx.x;
  const int wave = tid >> 6;          // 8 waves
  const int lane = tid & 63;
  const int mh   = wave & 1;          // batch half
  const int kseg = wave >> 1;         // K quarter (256)

  __shared__ float pbuf[2][32][64];   // reduced gates [mh][m][n]
  __shared__ float sbuf[8][8];        // proj cross-wave partials

  // ---- persistent weight fragments in VGPRs (bf16, MFMA B layout) ----
  const float* Wsrc = (role == 0) ? Wih1 : (role == 1) ? Whh1
                    : (role == 2) ? Wih2 : Whh2;
  const int Ksrc  = (role == 0) ? 800 : 1024;
  const int nrow  = lane & 31;
  const int khalf = (lane >> 5) * 8;
  bf16x8 bfr[16][2];
  #pragma unroll
  for (int ks = 0; ks < 16; ++ks) {
    #pragma unroll
    for (int nt = 0; nt < 2; ++nt) {
      const int nloc = nt * 32 + nrow;
      const int g = (role == 1 || role == 3)
                  ? ((nloc >> 4) * 1024 + sub * 16 + (nloc & 15))  // i/f/g/o interleave
                  : (sub * 64 + nloc);                             // natural slice
      const int k0 = kseg * 256 + ks * 16 + khalf;
      bf16x8 v;
      if (k0 + 8 <= Ksrc) {
        const float* wp = Wsrc + (size_t)g * (size_t)Ksrc + k0;
        #pragma unroll
        for (int j = 0; j < 8; ++j) v[j] = bf16bits(wp[j]);
      } else {
        #pragma unroll
        for (int j = 0; j < 8; ++j) v[j] = (short)0;
      }
      bfr[ks][nt] = v;
    }
  }

  float cst[2] = {0.f, 0.f};          // persistent c-state (b, hc) pairs
  const int brow = mh * 32 + (lane & 31);

  for (int tau = 0; tau < 604; ++tau) {
    const int sl = tau & 1;
    const bool active =
        (role == 0) ? (tau <= 599) :
        (role == 1) ? (tau >= 1 && tau <= 600) :
        (role == 2) ? (tau >= 2 && tau <= 601) :
                      (tau >= 3 && tau <= 602);
    f32x16 acc0, acc1;
    #pragma unroll
    for (int i = 0; i < 16; ++i) { acc0[i] = 0.f; acc1[i] = 0.f; }

    if (active) {
      const __hip_bfloat16* Asrc =
          (role == 0) ? (Xbuf + (size_t)tau * 65536)
        : (role == 3) ? (h2buf + sl * 65536)      // h2_{tau-4}
                      : (h1buf + sl * 65536);     // h1_{tau-2}
      const bf16x8* ap =
          reinterpret_cast<const bf16x8*>(Asrc + brow * 1024 + kseg * 256 + khalf);
      #pragma unroll
      for (int ks = 0; ks < 16; ++ks) {
        const bf16x8 a = ap[ks * 2];
        acc0 = __builtin_amdgcn_mfma_f32_32x32x16_bf16(a, bfr[ks][0], acc0, 0, 0, 0);
        acc1 = __builtin_amdgcn_mfma_f32_32x32x16_bf16(a, bfr[ks][1], acc1, 0, 0, 0);
      }
    }
    // ---- K-split partial reduction through LDS (4 rounds) ----
    #pragma unroll
    for (int r = 0; r < 4; ++r) {
      if (active && kseg == r) {
        #pragma unroll
        for (int reg = 0; reg < 16; ++reg) {
          const int mrow = (reg & 3) + 8 * (reg >> 2) + 4 * (lane >> 5);
          const int col  = lane & 31;
          if (r == 0) {
            pbuf[mh][mrow][col]      = acc0[reg];
            pbuf[mh][mrow][col + 32] = acc1[reg];
          } else {
            pbuf[mh][mrow][col]      += acc0[reg];
            pbuf[mh][mrow][col + 32] += acc1[reg];
          }
        }
      }
      __syncthreads();
    }
    // ---- consume ----
    if (active) {
      if (role == 0 || role == 2) {          // write P ring (+ both biases)
        float* Pdst = ((role == 0) ? P0 : P1) + sl * 262144;
        const float* bi = (role == 0) ? bih1 : bih2;
        const float* bh = (role == 0) ? bhh1 : bhh2;
        const int i0 = tid * 8;
        const int b  = i0 >> 6;
        const int c0 = i0 & 63;
        #pragma unroll
        for (int j = 0; j < 8; ++j) {
          const int col = c0 + j;
          const int g = sub * 64 + col;
          Pdst[b * 4096 + g] = pbuf[b >> 5][b & 31][col] + bi[g] + bh[g];
        }
      } else {                               // LSTM pointwise, publish h (bf16)
        __hip_bfloat16* hdst = ((role == 1) ? h1buf : h2buf) + ((tau + 1) & 1) * 65536;
        const float* Psrc = ((role == 1) ? P0 : P1) + ((tau + 1) & 1) * 262144;
        const int hc  = tid & 15;
        const int bb0 = (tid >> 4) * 2;
        #pragma unroll
        for (int e = 0; e < 2; ++e) {
          const int b = bb0 + e;
          const float* pr = &pbuf[b >> 5][b & 31][0];
          const float* psrc = Psrc + b * 4096 + sub * 16 + hc;
          const float gi = pr[hc]      + psrc[0];
          const float gf = pr[16 + hc] + psrc[1024];
          const float gg = pr[32 + hc] + psrc[2048];
          const float go = pr[48 + hc] + psrc[3072];
          const float c  = sigf(gf) * cst[e] + sigf(gi) * tanhf2(gg);
          cst[e] = c;
          hdst[b * 1024 + sub * 16 + hc] = __float2bfloat16(sigf(go) * tanhf2(c));
        }
      }
    }
    // ---- projection out_{tau-4} (all blocks: 5 cols x 4 batch rows) ----
    const bool pact = (tau >= 4);
    if (pact) {
      const __hip_bfloat16* h2s = h2buf + sl * 65536;           // h2_{tau-4}
      const __hip_bfloat16* xs  = Xbuf + (size_t)(tau - 4) * 65536;
      const int c0 = (bid & 15) * 5;
      const int b  = (bid >> 4) * 4 + (tid >> 7);
      const int kl = tid & 127;
      float pj[5];
      #pragma unroll
      for (int c = 0; c < 5; ++c) pj[c] = 0.f;
      for (int k = kl; k < 1568; k += 128) {
        const float a = (k < 1024) ? __bfloat162float(h2s[b * 1024 + k])
                                   : __bfloat162float(xs[b * 1024 + (k - 768)]);
        #pragma unroll
        for (int c = 0; c < 5; ++c)
          pj[c] += a * __bfloat162float(WprojB[(c0 + c) * 1568 + k]);
      }
      #pragma unroll
      for (int c = 0; c < 5; ++c) {
        #pragma unroll
        for (int off = 32; off > 0; off >>= 1)
          pj[c] += __shfl_xor(pj[c], off, 64);
      }
      if (lane == 0) {
        #pragma unroll
        for (int c = 0; c < 5; ++c) sbuf[wave][c] = pj[c];
      }
    }
    __syncthreads();
    if (pact && ((wave & 1) == 0) && lane == 0) {
      const int c0 = (bid & 15) * 5;
      const int b  = (bid >> 4) * 4 + (wave >> 1);
      #pragma unroll
      for (int c = 0; c < 5; ++c)
        out[b * 48000 + (c0 + c) * 600 + (tau - 4)] =
            sbuf[wave][c] + sbuf[wave + 1][c] + bproj[c0 + c];
    }
    __syncthreads();
    // ---- grid barrier (epoch counter, agent scope) ----
    if (tid == 0) {
      const unsigned int ep = (unsigned int)tau + 1u;
      const unsigned int old =
          __hip_atomic_fetch_add(&bar[0], 1u, __ATOMIC_ACQ_REL, __HIP_MEMORY_SCOPE_AGENT);
      if (old + 1u == ep * 256u) {
        __hip_atomic_store(&bar[32], ep, __ATOMIC_RELEASE, __HIP_MEMORY_SCOPE_AGENT);
      } else {
        while (__hip_atomic_load(&bar[32], __ATOMIC_ACQUIRE, __HIP_MEMORY_SCOPE_AGENT) < ep) {
          __builtin_amdgcn_s_sleep(2);
        }
      }
    }
    __syncthreads();
  }
}

// ---------------------------------------------------------------------------
extern "C" void kernel_launch(void* const* d_in, const int* in_sizes, int n_in,
                              void* d_out, int out_size, void* d_ws, size_t ws_size,
                              hipStream_t stream) {
  (void)in_sizes; (void)n_in; (void)out_size; (void)ws_size;
  const float* dur   = (const float*)d_in[0];   // [64][600][544]
  const float* dec   = (const float*)d_in[1];   // [64][80][600]
  const float* Wp1   = (const float*)d_in[3];
  const float* Wp2   = (const float*)d_in[4];
  const float* Wih1  = (const float*)d_in[5];
  const float* Whh1  = (const float*)d_in[6];
  const float* bih1  = (const float*)d_in[7];
  const float* bhh1  = (const float*)d_in[8];
  const float* Wih2  = (const float*)d_in[9];
  const float* Whh2  = (const float*)d_in[10];
  const float* bih2  = (const float*)d_in[11];
  const float* bhh2  = (const float*)d_in[12];
  const float* Wproj = (const float*)d_in[13];
  const float* bproj = (const float*)d_in[14];

  char* ws = (char*)d_ws;
  unsigned int*   bar  = (unsigned int*)(ws + 0);           // 256 B
  __hip_bfloat16* h1   = (__hip_bfloat16*)(ws + 256);       // 2x64x1024 bf16
  __hip_bfloat16* h2   = (__hip_bfloat16*)(ws + 262400);    // 2x64x1024 bf16
  float*          P0   = (float*)(ws + 524544);             // 2x64x4096 f32
  float*          P1   = (float*)(ws + 2621696);            // 2x64x4096 f32
  __hip_bfloat16* X    = (__hip_bfloat16*)(ws + 4718848);   // 600x64x1024 bf16
  float*          pn1  = (float*)(ws + 83362048);           // 600x64x256 f32
  __hip_bfloat16* WpjB = (__hip_bfloat16*)(ws + 122683648); // 80x1568 bf16

  // zero barrier + h-state double buffers (ws is poisoned 0xAA each launch)
  hipMemsetAsync(d_ws, 0, 524544, stream);

  prenet1_kernel<<<600, 256, 0, stream>>>(dec, Wp1, pn1);
  prenet2_kernel<<<dim3(600, 8), 256, 0, stream>>>(pn1, Wp2, X);
  xfill_kernel<<<115200, 256, 0, stream>>>(dur, X);
  wprojcvt_kernel<<<490, 256, 0, stream>>>(Wproj, WpjB);
  persist_kernel<<<256, 512, 0, stream>>>(Wih1, Whh1, bih1, bhh1,
                                          Wih2, Whh2, bih2, bhh2,
                                          WpjB, bproj, X, P0, P1, h1, h2,
                                          (float*)d_out, bar);
}

// Round 2
// 10929.497 us; speedup vs baseline: 1.4458x; 1.4458x over previous
//
#include <hip/hip_runtime.h>
#include <hip/hip_bf16.h>
#include <stdint.h>

// ---------------------------------------------------------------------------
// Tacotron2 decoder on MI355X — persistent pipelined recurrence.
// R2 change: ALL cross-block communication via RELAXED agent-scope atomics
// (sc-bit cache bypass, straight to/from coherent L3) — no acquire/release,
// so NO per-XCD L2 invalidate/writeback storms (the R1 killer: 25 us/tick).
// Barrier = per-tau flag array (parallel stores + parallel polls, no RMW).
// ---------------------------------------------------------------------------

typedef short  bf16x8  __attribute__((ext_vector_type(8)));
typedef float  f32x16  __attribute__((ext_vector_type(16)));

// ---------------- threefry2x32 (exact JAX semantics) ------------------------
__device__ __forceinline__ uint32_t rotl32(uint32_t x, int r) {
  return (x << r) | (x >> (32 - r));
}

__device__ __forceinline__ void tf2x32(uint32_t k0, uint32_t k1,
                                       uint32_t x0, uint32_t x1,
                                       uint32_t& o0, uint32_t& o1) {
  uint32_t k2 = k0 ^ k1 ^ 0x1BD11BDAu;
  x0 += k0; x1 += k1;
#define TF_R(r) { x0 += x1; x1 = rotl32(x1, r); x1 ^= x0; }
  TF_R(13) TF_R(15) TF_R(26) TF_R(6)   x0 += k1; x1 += k2 + 1u;
  TF_R(17) TF_R(29) TF_R(16) TF_R(24)  x0 += k2; x1 += k0 + 2u;
  TF_R(13) TF_R(15) TF_R(26) TF_R(6)   x0 += k0; x1 += k1 + 3u;
  TF_R(17) TF_R(29) TF_R(16) TF_R(24)  x0 += k1; x1 += k2 + 4u;
  TF_R(13) TF_R(15) TF_R(26) TF_R(6)   x0 += k2; x1 += k0 + 5u;
#undef TF_R
  o0 = x0; o1 = x1;
}

__device__ __forceinline__ void dropout_keys(uint32_t& a1, uint32_t& b1,
                                             uint32_t& a2, uint32_t& b2) {
  uint32_t o0, o1, p0, p1;
  tf2x32(0u, 42u, 0u, 2u, o0, o1);
  tf2x32(0u, 42u, 1u, 3u, p0, p1);
  a1 = o0; b1 = p0;
  a2 = o1; b2 = p1;
}

__device__ __forceinline__ bool keep_mask(uint32_t ka, uint32_t kb, uint32_t e) {
  const uint32_t H = 4923392u;       // (601*64*256)/2
  uint32_t o0, o1;
  if (e < H) { tf2x32(ka, kb, e, e + H, o0, o1); return o0 < 0x80000000u; }
  else       { tf2x32(ka, kb, e - H, e, o0, o1); return o1 < 0x80000000u; }
}

__device__ __forceinline__ float sigf(float x)  { return 1.f / (1.f + __expf(-x)); }
__device__ __forceinline__ float tanhf2(float x){ return 2.f / (1.f + __expf(-2.f * x)) - 1.f; }

__device__ __forceinline__ short bf16bits(float f) {
  __hip_bfloat16 h = __float2bfloat16(f);
  short s; __builtin_memcpy(&s, &h, 2);
  return s;
}
__device__ __forceinline__ float bflo(uint32_t u) {
  uint32_t x = u << 16; float f; __builtin_memcpy(&f, &x, 4); return f;
}
__device__ __forceinline__ float bfhi(uint32_t u) {
  uint32_t x = u & 0xffff0000u; float f; __builtin_memcpy(&f, &x, 4); return f;
}

// ---- relaxed agent-scope (L3-coherent, NO cache maintenance) accessors -----
__device__ __forceinline__ uint64_t ld_u64_a(const void* p) {
  return __hip_atomic_load((const uint64_t*)p, __ATOMIC_RELAXED, __HIP_MEMORY_SCOPE_AGENT);
}
__device__ __forceinline__ uint32_t ld_u32_a(const void* p) {
  return __hip_atomic_load((const uint32_t*)p, __ATOMIC_RELAXED, __HIP_MEMORY_SCOPE_AGENT);
}
__device__ __forceinline__ void st_u64_a(void* p, uint64_t v) {
  __hip_atomic_store((uint64_t*)p, v, __ATOMIC_RELAXED, __HIP_MEMORY_SCOPE_AGENT);
}
__device__ __forceinline__ void st_u32_a(void* p, uint32_t v) {
  __hip_atomic_store((uint32_t*)p, v, __ATOMIC_RELAXED, __HIP_MEMORY_SCOPE_AGENT);
}
__device__ __forceinline__ bf16x8 ld_frag_a(const __hip_bfloat16* p) {
  union { uint64_t u[2]; bf16x8 v; } c;
  c.u[0] = ld_u64_a(p);
  c.u[1] = ld_u64_a((const char*)p + 8);
  return c.v;
}

// ---------------- prenet layer 1 --------------------------------------------
__global__ void prenet1_kernel(const float* __restrict__ dec,
                               const float* __restrict__ Wp1,
                               float* __restrict__ pn1) {
  const int t = blockIdx.x;
  const int tid = threadIdx.x;
  __shared__ float          sdec[64][81];
  __shared__ __hip_bfloat16 sw1[256][80];
  for (int idx = tid; idx < 64 * 80; idx += 256) {
    int b = idx / 80, m = idx - b * 80;
    sdec[b][m] = (t == 0) ? 0.f : dec[b * 48000 + m * 600 + (t - 1)];
  }
  for (int idx = tid; idx < 256 * 80; idx += 256) {
    int j = idx / 80, k = idx - j * 80;
    sw1[j][k] = __float2bfloat16(Wp1[idx]);
  }
  __syncthreads();
  uint32_t ka, kb, ka2, kb2;
  dropout_keys(ka, kb, ka2, kb2);
  const int b  = tid & 63;
  const int jg = tid >> 6;
  for (int jj = 0; jj < 64; ++jj) {
    const int j = jg * 64 + jj;
    float acc = 0.f;
    #pragma unroll
    for (int k = 0; k < 80; ++k)
      acc += sdec[b][k] * __bfloat162float(sw1[j][k]);
    const uint32_t e = (uint32_t)((t * 64 + b) * 256 + j);
    pn1[(t * 64 + b) * 256 + j] =
        keep_mask(ka, kb, e) ? 2.f * fmaxf(acc, 0.f) : 0.f;
  }
}

// ---------------- prenet layer 2 -> X[t][b][0..255] (bf16) ------------------
__global__ void prenet2_kernel(const float* __restrict__ pn1,
                               const float* __restrict__ Wp2,
                               __hip_bfloat16* __restrict__ X) {
  const int t  = blockIdx.x;
  const int j0 = blockIdx.y * 32;
  const int tid = threadIdx.x;
  __shared__ __hip_bfloat16 sact[64][258];
  __shared__ __hip_bfloat16 sw[32][256];
  for (int idx = tid; idx < 64 * 256; idx += 256) {
    int b = idx >> 8, k = idx & 255;
    sact[b][k] = __float2bfloat16(pn1[(t * 64 + b) * 256 + k]);
  }
  for (int idx = tid; idx < 32 * 256; idx += 256) {
    int r = idx >> 8, k = idx & 255;
    sw[r][k] = __float2bfloat16(Wp2[(j0 + r) * 256 + k]);
  }
  __syncthreads();
  uint32_t ka, kb, ka2, kb2;
  dropout_keys(ka, kb, ka2, kb2);
  const int b  = tid & 63;
  const int jg = tid >> 6;
  float acc[8];
  #pragma unroll
  for (int c = 0; c < 8; ++c) acc[c] = 0.f;
  for (int k = 0; k < 256; ++k) {
    const float a = __bfloat162float(sact[b][k]);
    #pragma unroll
    for (int c = 0; c < 8; ++c)
      acc[c] += a * __bfloat162float(sw[jg * 8 + c][k]);
  }
  #pragma unroll
  for (int c = 0; c < 8; ++c) {
    const int j = j0 + jg * 8 + c;
    const uint32_t e = (uint32_t)((t * 64 + b) * 256 + j);
    const float v = keep_mask(ka2, kb2, e) ? 2.f * fmaxf(acc[c], 0.f) : 0.f;
    X[(t * 64 + b) * 1024 + j] = __float2bfloat16(v);
  }
}

// ---------------- X[t][b][256..799] = dur[b][t][:], [800..1023] = 0 ---------
__global__ void xfill_kernel(const float* __restrict__ dur,
                             __hip_bfloat16* __restrict__ X) {
  const int idx = blockIdx.x * 256 + threadIdx.x;
  const int t  = idx / 49152;
  const int r  = idx - t * 49152;
  const int b  = r / 768;
  const int kk = r - b * 768;
  const float v = (kk < 544) ? dur[(b * 600 + t) * 544 + kk] : 0.f;
  X[(t * 64 + b) * 1024 + 256 + kk] = __float2bfloat16(v);
}

__global__ void wprojcvt_kernel(const float* __restrict__ W,
                                __hip_bfloat16* __restrict__ Wb) {
  const int idx = blockIdx.x * 256 + threadIdx.x;
  Wb[idx] = __float2bfloat16(W[idx]);
}

// ---------------- persistent pipelined recurrence ---------------------------
__launch_bounds__(512, 2)
__global__ void persist_kernel(
    const float* __restrict__ Wih1, const float* __restrict__ Whh1,
    const float* __restrict__ bih1, const float* __restrict__ bhh1,
    const float* __restrict__ Wih2, const float* __restrict__ Whh2,
    const float* __restrict__ bih2, const float* __restrict__ bhh2,
    const __hip_bfloat16* __restrict__ WprojB, const float* __restrict__ bproj,
    const __hip_bfloat16* __restrict__ Xbuf,
    float* __restrict__ P0, float* __restrict__ P1,
    __hip_bfloat16* __restrict__ h1buf, __hip_bfloat16* __restrict__ h2buf,
    uint32_t* __restrict__ flags,
    float* __restrict__ out) {
  const int bid  = blockIdx.x;
  const int role = bid >> 6;          // 0:AX 1:AF 2:B1 3:BF
  const int sub  = bid & 63;
  const int tid  = threadIdx.x;
  const int wave = tid >> 6;          // 8 waves
  const int lane = tid & 63;
  const int mh   = wave & 1;          // batch half
  const int kseg = wave >> 1;         // K quarter (256)

  __shared__ float pbuf[2][32][64];   // reduced gates [mh][m][n]
  __shared__ float sbuf[8][8];        // proj cross-wave partials

  // ---- persistent weight fragments in VGPR/AGPR (bf16, MFMA B layout) ----
  const float* Wsrc = (role == 0) ? Wih1 : (role == 1) ? Whh1
                    : (role == 2) ? Wih2 : Whh2;
  const int Ksrc  = (role == 0) ? 800 : 1024;
  const int nrow  = lane & 31;
  const int khalf = (lane >> 5) * 8;
  bf16x8 bfr[16][2];
  #pragma unroll
  for (int ks = 0; ks < 16; ++ks) {
    #pragma unroll
    for (int nt = 0; nt < 2; ++nt) {
      const int nloc = nt * 32 + nrow;
      const int g = (role == 1 || role == 3)
                  ? ((nloc >> 4) * 1024 + sub * 16 + (nloc & 15))
                  : (sub * 64 + nloc);
      const int k0 = kseg * 256 + ks * 16 + khalf;
      bf16x8 v;
      if (k0 + 8 <= Ksrc) {
        const float* wp = Wsrc + (size_t)g * (size_t)Ksrc + k0;
        #pragma unroll
        for (int j = 0; j < 8; ++j) v[j] = bf16bits(wp[j]);
      } else {
        #pragma unroll
        for (int j = 0; j < 8; ++j) v[j] = (short)0;
      }
      bfr[ks][nt] = v;
    }
  }

  // ---- bias registers (role 0/2 write path): 8 consecutive gate cols ------
  float breg[8];
  if (role == 0 || role == 2) {
    const float* bi = (role == 0) ? bih1 : bih2;
    const float* bh = (role == 0) ? bhh1 : bhh2;
    const int c0 = (tid * 8) & 63;
    #pragma unroll
    for (int j = 0; j < 8; ++j) {
      const int g = sub * 64 + c0 + j;
      breg[j] = bi[g] + bh[g];
    }
  }

  float cst[2] = {0.f, 0.f};          // c-state: (b = tid>>3, cols hcp, hcp+1)
  const int brow = mh * 32 + (lane & 31);

  for (int tau = 0; tau < 604; ++tau) {
    const int sl = tau & 1;
    const bool active =
        (role == 0) ? (tau <= 599) :
        (role == 1) ? (tau >= 1 && tau <= 600) :
        (role == 2) ? (tau >= 2 && tau <= 601) :
                      (tau >= 3 && tau <= 602);
    f32x16 acc0, acc1;
    #pragma unroll
    for (int i = 0; i < 16; ++i) { acc0[i] = 0.f; acc1[i] = 0.f; }

    if (active) {
      if (role == 0) {
        // X is read-only: normal cached vector loads (stays in L2 now)
        const bf16x8* ap = reinterpret_cast<const bf16x8*>(
            Xbuf + (size_t)tau * 65536 + brow * 1024 + kseg * 256 + khalf);
        #pragma unroll
        for (int ks = 0; ks < 16; ++ks) {
          const bf16x8 a = ap[ks * 2];
          acc0 = __builtin_amdgcn_mfma_f32_32x32x16_bf16(a, bfr[ks][0], acc0, 0, 0, 0);
          acc1 = __builtin_amdgcn_mfma_f32_32x32x16_bf16(a, bfr[ks][1], acc1, 0, 0, 0);
        }
      } else {
        // h ring buffers are cross-block comm: L1/L2-bypass loads
        const __hip_bfloat16* Asrc =
            ((role == 3) ? h2buf : h1buf) + sl * 65536;
        const __hip_bfloat16* ap = Asrc + brow * 1024 + kseg * 256 + khalf;
        #pragma unroll
        for (int ks = 0; ks < 16; ++ks) {
          const bf16x8 a = ld_frag_a(ap + ks * 16);
          acc0 = __builtin_amdgcn_mfma_f32_32x32x16_bf16(a, bfr[ks][0], acc0, 0, 0, 0);
          acc1 = __builtin_amdgcn_mfma_f32_32x32x16_bf16(a, bfr[ks][1], acc1, 0, 0, 0);
        }
      }
    }
    // ---- K-split partial reduction through LDS (4 rounds) ----
    #pragma unroll
    for (int r = 0; r < 4; ++r) {
      if (active && kseg == r) {
        #pragma unroll
        for (int reg = 0; reg < 16; ++reg) {
          const int mrow = (reg & 3) + 8 * (reg >> 2) + 4 * (lane >> 5);
          const int col  = lane & 31;
          if (r == 0) {
            pbuf[mh][mrow][col]      = acc0[reg];
            pbuf[mh][mrow][col + 32] = acc1[reg];
          } else {
            pbuf[mh][mrow][col]      += acc0[reg];
            pbuf[mh][mrow][col + 32] += acc1[reg];
          }
        }
      }
      __syncthreads();
    }
    // ---- consume ----
    if (active) {
      if (role == 0 || role == 2) {   // write P ring (write-through pairs)
        float* Pdst = ((role == 0) ? P0 : P1) + sl * 262144;
        const int i0 = tid * 8;
        const int b  = i0 >> 6;
        const int c0 = i0 & 63;
        float* dst = Pdst + b * 4096 + sub * 64 + c0;
        const float* pr = &pbuf[b >> 5][b & 31][0];
        #pragma unroll
        for (int j = 0; j < 8; j += 2) {
          union { float f[2]; uint64_t u; } w;
          w.f[0] = pr[c0 + j]     + breg[j];
          w.f[1] = pr[c0 + j + 1] + breg[j + 1];
          st_u64_a(dst + j, w.u);
        }
      } else {                        // LSTM pointwise, publish h (bf16 pairs)
        __hip_bfloat16* hdst = ((role == 1) ? h1buf : h2buf) + ((tau + 1) & 1) * 65536;
        const float* Psrc = ((role == 1) ? P0 : P1) + ((tau + 1) & 1) * 262144;
        const int hcp = (tid & 7) * 2;
        const int b   = tid >> 3;
        const float* pr = &pbuf[b >> 5][b & 31][0];
        const uint64_t* q = (const uint64_t*)(Psrc + b * 4096 + sub * 16 + hcp);
        union { uint64_t u; float f[2]; } pi, pf, pg, po;
        pi.u = ld_u64_a(q);
        pf.u = ld_u64_a(q + 512);
        pg.u = ld_u64_a(q + 1024);
        po.u = ld_u64_a(q + 1536);
        uint32_t hw = 0;
        #pragma unroll
        for (int j = 0; j < 2; ++j) {
          const float gi = pr[hcp + j]      + pi.f[j];
          const float gf = pr[16 + hcp + j] + pf.f[j];
          const float gg = pr[32 + hcp + j] + pg.f[j];
          const float go = pr[48 + hcp + j] + po.f[j];
          const float c  = sigf(gf) * cst[j] + sigf(gi) * tanhf2(gg);
          cst[j] = c;
          const uint32_t hb = (uint32_t)(uint16_t)bf16bits(sigf(go) * tanhf2(c));
          hw |= hb << (16 * j);
        }
        st_u32_a(hdst + b * 1024 + sub * 16 + hcp, hw);
      }
    }
    // ---- projection out_{tau-4} (all blocks: 5 cols x 4 batch rows) ----
    const bool pact = (tau >= 4);
    if (pact) {
      const __hip_bfloat16* h2s = h2buf + sl * 65536;           // h2_{tau-4}
      const __hip_bfloat16* xs  = Xbuf + (size_t)(tau - 4) * 65536;
      const int c0 = (bid & 15) * 5;
      const int b  = (bid >> 4) * 4 + (tid >> 7);
      const int kl = tid & 127;
      float pj[5];
      #pragma unroll
      for (int c = 0; c < 5; ++c) pj[c] = 0.f;
      for (int k2 = kl * 2; k2 < 1568; k2 += 256) {
        float a0, a1;
        if (k2 < 1024) {
          const uint32_t u = ld_u32_a(h2s + b * 1024 + k2);      // comm: bypass
          a0 = bflo(u); a1 = bfhi(u);
        } else {
          const uint32_t u = *(const uint32_t*)(xs + b * 1024 + (k2 - 768));
          a0 = bflo(u); a1 = bfhi(u);
        }
        #pragma unroll
        for (int c = 0; c < 5; ++c) {
          const uint32_t w = *(const uint32_t*)(WprojB + (c0 + c) * 1568 + k2);
          pj[c] += a0 * bflo(w) + a1 * bfhi(w);
        }
      }
      #pragma unroll
      for (int c = 0; c < 5; ++c) {
        #pragma unroll
        for (int off = 32; off > 0; off >>= 1)
          pj[c] += __shfl_xor(pj[c], off, 64);
      }
      if (lane == 0) {
        #pragma unroll
        for (int c = 0; c < 5; ++c) sbuf[wave][c] = pj[c];
      }
    }
    __syncthreads();
    if (pact && ((wave & 1) == 0) && lane == 0) {
      const int c0 = (bid & 15) * 5;
      const int b  = (bid >> 4) * 4 + (wave >> 1);
      #pragma unroll
      for (int c = 0; c < 5; ++c)
        out[b * 48000 + (c0 + c) * 600 + (tau - 4)] =
            sbuf[wave][c] + sbuf[wave + 1][c] + bproj[c0 + c];
    }
    // ---- grid barrier: per-tau flag array, relaxed ops only ----
    // __syncthreads() drains each wave's vmcnt before s_barrier, so all of
    // this block's write-through stores (and comm reads) are complete.
    __syncthreads();
    if (tid == 0) st_u32_a(flags + (size_t)tau * 256 + bid, 1u);
    if (wave == 0) {
      const uint32_t* f = flags + (size_t)tau * 256;
      for (;;) {
        const uint32_t a0 = ld_u32_a(f + lane);
        const uint32_t a1 = ld_u32_a(f + 64 + lane);
        const uint32_t a2 = ld_u32_a(f + 128 + lane);
        const uint32_t a3 = ld_u32_a(f + 192 + lane);
        if (__all((int)(a0 & a1 & a2 & a3))) break;
        __builtin_amdgcn_s_sleep(1);
      }
    }
    __syncthreads();
  }
}

// ---------------------------------------------------------------------------
extern "C" void kernel_launch(void* const* d_in, const int* in_sizes, int n_in,
                              void* d_out, int out_size, void* d_ws, size_t ws_size,
                              hipStream_t stream) {
  (void)in_sizes; (void)n_in; (void)out_size; (void)ws_size;
  const float* dur   = (const float*)d_in[0];   // [64][600][544]
  const float* dec   = (const float*)d_in[1];   // [64][80][600]
  const float* Wp1   = (const float*)d_in[3];
  const float* Wp2   = (const float*)d_in[4];
  const float* Wih1  = (const float*)d_in[5];
  const float* Whh1  = (const float*)d_in[6];
  const float* bih1  = (const float*)d_in[7];
  const float* bhh1  = (const float*)d_in[8];
  const float* Wih2  = (const float*)d_in[9];
  const float* Whh2  = (const float*)d_in[10];
  const float* bih2  = (const float*)d_in[11];
  const float* bhh2  = (const float*)d_in[12];
  const float* Wproj = (const float*)d_in[13];
  const float* bproj = (const float*)d_in[14];

  char* ws = (char*)d_ws;
  // layout:
  //   X    @ 0            : 600*64*1024*2 = 78,643,200
  //   WpjB @ 78,643,200   : 80*1568*2     =    250,880
  //   comm @ 78,894,080   : flags 618,496 | h1 262,144 | h2 262,144
  //                         | P0 2,097,152 | P1 2,097,152   (= 5,337,088)
  //   pn1  @ 78,894,080   : 600*64*256*4  = 39,321,600  (OVERLAPS comm —
  //        pn1 is dead after prenet2; memset of flags/h runs after prenet2)
  __hip_bfloat16* X    = (__hip_bfloat16*)(ws + 0);
  __hip_bfloat16* WpjB = (__hip_bfloat16*)(ws + 78643200);
  char*           comm = ws + 78894080;
  uint32_t*       flags= (uint32_t*)(comm + 0);         // 604*256*4 = 618,496
  __hip_bfloat16* h1   = (__hip_bfloat16*)(comm + 618496);
  __hip_bfloat16* h2   = (__hip_bfloat16*)(comm + 880640);
  float*          P0   = (float*)(comm + 1142784);
  float*          P1   = (float*)(comm + 3239936);
  float*          pn1  = (float*)(ws + 78894080);

  prenet1_kernel<<<600, 256, 0, stream>>>(dec, Wp1, pn1);
  prenet2_kernel<<<dim3(600, 8), 256, 0, stream>>>(pn1, Wp2, X);
  // zero flags + h1 + h2 (contiguous 1,142,784 B) AFTER pn1 is consumed
  hipMemsetAsync(comm, 0, 1142784, stream);
  xfill_kernel<<<115200, 256, 0, stream>>>(dur, X);
  wprojcvt_kernel<<<490, 256, 0, stream>>>(Wproj, WpjB);
  persist_kernel<<<256, 512, 0, stream>>>(Wih1, Whh1, bih1, bhh1,
                                          Wih2, Whh2, bih2, bhh2,
                                          WpjB, bproj, X, P0, P1, h1, h2,
                                          flags, (float*)d_out);
}